// Round 12
// baseline (23.715 us; speedup 1.0000x reference)
//
#include <hip/hip_runtime.h>

// BiorUpSampling: 2x zero-interleaved upsample + separable symmetric 9-tap
// filter, SAME zero padding. Polyphase. PHASE-SEPARATED structure:
//   phase 1: issue ALL row loads (6-deep rolling), h-filter each row as it
//            lands  -> every vmcnt wait has only LOADS outstanding.
//   phase 2: vertical filter + 16 NT stores, ZERO vmcnt waits.
// Rationale: loads and stores share the in-order vmcnt counter on CDNA;
// interleaving them (R6/R10) made every load-consume wait drain the NT
// store queue (~HBM write-ack latency) from prior iterations.

constexpr int H = 512, W = 512;
constexpr int RP = 8;    // input rows advanced per block -> 16 output rows
constexpr int NR = RP + 4;  // 12 rows consumed per block

typedef float f32x4 __attribute__((ext_vector_type(4)));

__global__ __launch_bounds__(256, 4)
void bior_up_kernel(const float* __restrict__ in, float* __restrict__ out) {
  constexpr float E0 =  0.03782845550699535f;
  constexpr float E1 = -0.1106244044184226f;
  constexpr float E2 =  0.8526986790094022f;
  constexpr float E3 = -0.1106244044184226f;
  constexpr float E4 =  0.03782845550699535f;
  constexpr float O0 = -0.02384946501937986f;
  constexpr float O1 =  0.3774028556126536f;
  constexpr float O2 =  0.3774028556126537f;
  constexpr float O3 = -0.02384946501937986f;

  const int tid = threadIdx.x;
  const int r0  = blockIdx.x * RP;
  const int b   = blockIdx.y;
  const float* inb  = in  + (size_t)b * H * W;
  float*       outb = out + (size_t)b * (2 * H) * (2 * W);

  const int c = 2 * tid;              // this thread's input cols: c, c+1
  const bool lv = (c >= 2);
  const bool rv = (c <= W - 4);

  auto loadrow = [&](int gr, float2& L, float2& M, float2& R) {
    const bool rowv = ((unsigned)gr < (unsigned)H);
    const float* rowp = inb + (size_t)gr * W;
    const float2 z = make_float2(0.0f, 0.0f);
    L = (rowv && lv) ? *reinterpret_cast<const float2*>(rowp + c - 2) : z;
    M =  rowv        ? *reinterpret_cast<const float2*>(rowp + c)     : z;
    R = (rowv && rv) ? *reinterpret_cast<const float2*>(rowp + c + 2) : z;
  };
  auto hfilt = [&](float2 L, float2 M, float2 R,
                   float& a, float& bb, float& cc, float& dd) {
    const float v0 = L.x, v1 = L.y, v2 = M.x, v3 = M.y, v4 = R.x, v5 = R.y;
    a  = v0*E0 + v1*E1 + v2*E2 + v3*E3 + v4*E4;   // he(c)   -> out col 2c
    bb = v1*O0 + v2*O1 + v3*O2 + v4*O3;           // ho(c)   -> out col 2c+1
    cc = v1*E0 + v2*E1 + v3*E2 + v4*E3 + v5*E4;   // he(c+1) -> out col 2c+2
    dd = v2*O0 + v3*O1 + v4*O2 + v5*O3;           // ho(c+1) -> out col 2c+3
  };

  // All arrays constant-indexed after full unroll (no scratch).
  float2 Lr[NR], Mr[NR], Rr[NR];      // raw loads (lifetime ends at hfilt)
  float A[NR], B[NR], C[NR], D[NR];   // horizontally-filtered rows

  // ---- phase 1: rolling 6-deep load issue + h-filter (loads only) ----
#pragma unroll
  for (int i = 0; i < 6; ++i) loadrow(r0 - 2 + i, Lr[i], Mr[i], Rr[i]);
#pragma unroll
  for (int i = 0; i < NR; ++i) {
    if (i + 6 < NR) loadrow(r0 + 4 + i, Lr[i + 6], Mr[i + 6], Rr[i + 6]);
    hfilt(Lr[i], Mr[i], Rr[i], A[i], B[i], C[i], D[i]);
  }

  // ---- phase 2: vertical filter + NT stores (no vmcnt waits) ----
#pragma unroll
  for (int p = 0; p < RP; ++p) {
    f32x4 ev, od;
    ev.x = A[p]*E0 + A[p+1]*E1 + A[p+2]*E2 + A[p+3]*E3 + A[p+4]*E4;
    ev.y = B[p]*E0 + B[p+1]*E1 + B[p+2]*E2 + B[p+3]*E3 + B[p+4]*E4;
    ev.z = C[p]*E0 + C[p+1]*E1 + C[p+2]*E2 + C[p+3]*E3 + C[p+4]*E4;
    ev.w = D[p]*E0 + D[p+1]*E1 + D[p+2]*E2 + D[p+3]*E3 + D[p+4]*E4;
    od.x = A[p+1]*O0 + A[p+2]*O1 + A[p+3]*O2 + A[p+4]*O3;
    od.y = B[p+1]*O0 + B[p+2]*O1 + B[p+3]*O2 + B[p+4]*O3;
    od.z = C[p+1]*O0 + C[p+2]*O1 + C[p+3]*O2 + C[p+4]*O3;
    od.w = D[p+1]*O0 + D[p+2]*O1 + D[p+3]*O2 + D[p+4]*O3;

    const int row_e = 2 * (r0 + p);
    f32x4* pe = reinterpret_cast<f32x4*>(&outb[(size_t)row_e       * (2 * W) + 4 * tid]);
    f32x4* po = reinterpret_cast<f32x4*>(&outb[(size_t)(row_e + 1) * (2 * W) + 4 * tid]);
    __builtin_nontemporal_store(ev, pe);
    __builtin_nontemporal_store(od, po);
  }
}

extern "C" void kernel_launch(void* const* d_in, const int* in_sizes, int n_in,
                              void* d_out, int out_size, void* d_ws, size_t ws_size,
                              hipStream_t stream) {
  const float* in = (const float*)d_in[0];
  float* out = (float*)d_out;
  const int batch = in_sizes[0] / (H * W);
  dim3 grid(H / RP, batch);   // 64 x 16 = 1024 blocks -> 4 blocks/CU
  bior_up_kernel<<<grid, 256, 0, stream>>>(in, out);
}